// Round 4
// baseline (366.692 us; speedup 1.0000x reference)
//
#include <hip/hip_runtime.h>
#include <hip/hip_bf16.h>

// EdgeDetourHead: B=2, N=512, E=128, H=256
// h1 = relu( [ |h_i-h_j| | h_j | e_ij ] @ [W1c; W1b; w1d] + PA[i] )   (PA = h_i@W1a + b1, fp32)
// h2 = relu( h1@W2 + b2 ) ;  p = h2@W3 + b3 ;  out = 0.5*(p+p^T), zero diag
//
// R4: pipelined persistent-ish WGs. 1 WG (4 waves, 102 KB LDS) per CU; each WG
// runs TILES_PER_WG tiles (M=128 pairs x N=256 cols) with 2 barriers/tile and
// heterogeneous spans (MFMA + VALU + LDS + global mixed in every span) so pipes
// overlap instead of summing. Layer 3 from registers (shuffle reduce) - h2 never
// hits LDS.

#define BN 512
#define EE 128
#define HH 256
#define TILES_PER_WG 8          // grid = 4096 tiles / 8 = 512 WGs

typedef __attribute__((ext_vector_type(8)))  short short8;
typedef __attribute__((ext_vector_type(16))) float f32x16;
typedef __attribute__((ext_vector_type(4)))  float f32x4;

static __device__ __forceinline__ unsigned short f2bf(float f) {
    __bf16 h = (__bf16)f;
    return __builtin_bit_cast(unsigned short, h);
}
static __device__ __forceinline__ f32x16 zero16() {
    f32x16 v;
    #pragma unroll
    for (int i = 0; i < 16; ++i) v[i] = 0.f;
    return v;
}
#define MFMA(a, b, c) __builtin_amdgcn_mfma_f32_32x32x16_bf16((a), (b), (c), 0, 0, 0)

// ---------------- kernel 0: pack weights + node A-frags into MFMA order ----------------
// B-frag (32x32x16): lane l holds B[k=(l>>5)*8+t][n=l&31], t=0..7.
// A-frag:            lane l holds A[m=l&31][k=(l>>5)*8+t].
__global__ void pack_all(const float* __restrict__ node, const float* __restrict__ W1,
                         const float* __restrict__ W2,
                         unsigned short* __restrict__ w1c_p, unsigned short* __restrict__ w1b_p,
                         unsigned short* __restrict__ w2_p,  unsigned short* __restrict__ w1d_f,
                         unsigned short* __restrict__ node_p) {
    int idx = blockIdx.x * 256 + threadIdx.x;          // 0..131071
    {   // node A-frags: frag (b, j32 0..15, kb 0..7)
        int t = idx & 7, l = (idx >> 3) & 63, kb = (idx >> 9) & 7;
        int j32 = (idx >> 12) & 15, b = (idx >> 16) & 1;
        int j = j32 * 32 + (l & 31), e = kb * 16 + (l >> 5) * 8 + t;
        node_p[idx] = f2bf(node[((size_t)b * BN + j) * EE + e]);
    }
    if (idx < 65536) {                                 // W2: kb 0..15
        int t = idx & 7, l = (idx >> 3) & 63, nb = (idx >> 9) & 7, kb = idx >> 12;
        int k = kb * 16 + (l >> 5) * 8 + t, n = nb * 32 + (l & 31);
        w2_p[idx] = f2bf(W2[k * HH + n]);
        if (idx < 32768) {                             // W1c rows 256..383, W1b rows 128..255
            w1c_p[idx] = f2bf(W1[(2 * EE + k) * HH + n]);
            w1b_p[idx] = f2bf(W1[(EE + k) * HH + n]);
        }
    }
    if (idx < 4096) {                                  // rank-1 B-frag: w1d (row 384)
        int t = idx & 7, l = (idx >> 3) & 63, nb = idx >> 9;
        int n = nb * 32 + (l & 31);
        bool nz = (t == 0 && l < 32);
        w1d_f[idx] = nz ? f2bf(W1[(3 * EE) * HH + n]) : (unsigned short)0;
    }
}

// ---------------- kernel 1: PA = h@W1a + b1 (fp32, exact) ----------------
__global__ void precompute_pa(const float* __restrict__ node, const float* __restrict__ W1,
                              const float* __restrict__ b1, float* __restrict__ PA) {
    int bi = blockIdx.x, h = threadIdx.x;
    const float* nd = node + (size_t)bi * EE;
    float sa = b1[h];
    #pragma unroll 8
    for (int e = 0; e < EE; ++e) sa += nd[e] * W1[e * HH + h];
    PA[bi * HH + h] = sa;
}

// ---------------- kernel 2: pipelined fused main ----------------
__global__ __launch_bounds__(256, 1) void edge_main(
    const float* __restrict__ node, const float* __restrict__ euclid,
    const float* __restrict__ W3, const float* __restrict__ b3,
    const float* __restrict__ b2v, const float* __restrict__ PA,
    const unsigned short* __restrict__ w1c_p, const unsigned short* __restrict__ w1b_p,
    const unsigned short* __restrict__ w2_p,  const unsigned short* __restrict__ w1d_f,
    const unsigned short* __restrict__ node_p,
    float* __restrict__ out)
{
    __shared__ __align__(16) unsigned short lds_D[128 * 136];   // 34816 B
    __shared__ __align__(16) unsigned short lds_h1[128 * 264];  // 67584 B
    __shared__ float pp[512];                                   // 2048 B

    const int wg = blockIdx.x;
    const int tid = threadIdx.x, wave = tid >> 6, lane = tid & 63;
    const int m0 = lane & 31, q = lane >> 5, kq = q * 8;
    const int col0 = wave * 64 + m0;

    // hoisted per-lane constants (tile-invariant)
    const float w30 = W3[col0], w31 = W3[col0 + 32];
    const float b20 = b2v[col0], b21 = b2v[col0 + 32];
    const float b3v = b3[0];
    const short8 d0 = ((const short8*)w1d_f)[(wave * 2 + 0) * 64 + lane];
    const short8 d1 = ((const short8*)w1d_f)[(wave * 2 + 1) * 64 + lane];

    // ---- D-build helper (inlined via lambda) ----
    auto buildD = [&](int g) {
        int b = g >> 11, i = (g >> 2) & 511, jbase = (g & 3) * 128;
        int row = tid >> 1, half = tid & 1;
        const f32x4* nj = (const f32x4*)(node + ((size_t)b * BN + jbase + row) * EE);
        const f32x4* hv = (const f32x4*)(node + ((size_t)b * BN + i) * EE);
        unsigned short* dst = &lds_D[row * 136 + half * 64];
        #pragma unroll
        for (int gg = 0; gg < 8; ++gg) {
            int c0 = half * 16 + gg * 2;               // f32x4 index (8 floats per gg)
            f32x4 a0 = nj[c0], a1 = nj[c0 + 1];
            f32x4 h0 = hv[c0], h1v = hv[c0 + 1];
            short8 pd;
            #pragma unroll
            for (int u = 0; u < 4; ++u) {
                pd[u]     = (short)f2bf(fabsf(a0[u] - h0[u]));
                pd[4 + u] = (short)f2bf(fabsf(a1[u] - h1v[u]));
            }
            *(short8*)(dst + gg * 8) = pd;
        }
    };

    // prologue: build D for first tile
    buildD(wg * TILES_PER_WG);
    __syncthreads();

    #pragma unroll 1
    for (int t = 0; t < TILES_PER_WG; ++t) {
        const int g = wg * TILES_PER_WG + t;
        const int b = g >> 11, i = (g >> 2) & 511, jbase = (g & 3) * 128;

        // ================= span A: store p(t-1), K1(t), epi1(t) =================
        if (t > 0 && tid < 128) {
            const int gp = g - 1;
            int bp = gp >> 11, ip = (gp >> 2) & 511, jp = gp & 3;
            float v = pp[tid] + pp[128 + tid] + pp[256 + tid] + pp[384 + tid] + b3v;
            out[((size_t)bp * BN + ip) * BN + jp * 128 + tid] = v;
        }

        f32x16 acc[4][2];
        #pragma unroll
        for (int mt = 0; mt < 4; ++mt) { acc[mt][0] = zero16(); acc[mt][1] = zero16(); }
        {
            const short8* bc = (const short8*)w1c_p;
            const short8* bb = (const short8*)w1b_p;
            const short8* np = (const short8*)node_p;
            const int npb = b * 128 + (g & 3) * 32;    // b*16*8 + jt*4*8 frags
            #pragma unroll
            for (int kb = 0; kb < 8; ++kb) {
                short8 b0 = bc[(kb * 8 + wave * 2 + 0) * 64 + lane];
                short8 b1 = bc[(kb * 8 + wave * 2 + 1) * 64 + lane];
                short8 c0 = bb[(kb * 8 + wave * 2 + 0) * 64 + lane];
                short8 c1 = bb[(kb * 8 + wave * 2 + 1) * 64 + lane];
                #pragma unroll
                for (int mt = 0; mt < 4; ++mt) {
                    short8 ad = *(const short8*)&lds_D[(mt * 32 + m0) * 136 + kb * 16 + kq];
                    short8 ah = np[(npb + mt * 8 + kb) * 64 + lane];
                    acc[mt][0] = MFMA(ad, b0, acc[mt][0]);
                    acc[mt][1] = MFMA(ad, b1, acc[mt][1]);
                    acc[mt][0] = MFMA(ah, c0, acc[mt][0]);
                    acc[mt][1] = MFMA(ah, c1, acc[mt][1]);
                }
            }
            // rank-1 e*w1d
            const float* erow = euclid + ((size_t)b * BN + i) * BN + jbase;
            #pragma unroll
            for (int mt = 0; mt < 4; ++mt) {
                short8 ae;
                #pragma unroll
                for (int u = 0; u < 8; ++u) ae[u] = 0;
                if (lane < 32) ae[0] = (short)f2bf(erow[mt * 32 + m0]);
                acc[mt][0] = MFMA(ae, d0, acc[mt][0]);
                acc[mt][1] = MFMA(ae, d1, acc[mt][1]);
            }
        }
        // epi1: h1 = relu(acc + PA[i]) -> lds_h1 (bf16, stride 264)
        {
            const float* paRow = PA + ((size_t)b * BN + i) * HH;
            float pa0 = paRow[col0], pa1 = paRow[col0 + 32];
            int rq = 4 * q;
            #pragma unroll
            for (int mt = 0; mt < 4; ++mt) {
                #pragma unroll
                for (int r = 0; r < 16; ++r) {
                    int row = mt * 32 + (r & 3) + 8 * (r >> 2) + rq;
                    float v0 = acc[mt][0][r] + pa0; v0 = v0 > 0.f ? v0 : 0.f;
                    float v1 = acc[mt][1][r] + pa1; v1 = v1 > 0.f ? v1 : 0.f;
                    lds_h1[row * 264 + col0]      = f2bf(v0);
                    lds_h1[row * 264 + col0 + 32] = f2bf(v1);
                }
            }
        }
        __syncthreads();

        // ================= span B: K2(t), epi2+L3reg(t), buildD(t+1) =================
        f32x16 c2[4][2];
        #pragma unroll
        for (int mt = 0; mt < 4; ++mt) { c2[mt][0] = zero16(); c2[mt][1] = zero16(); }
        {
            const short8* bp = (const short8*)w2_p;
            #pragma unroll
            for (int kb = 0; kb < 16; ++kb) {
                short8 b0 = bp[(kb * 8 + wave * 2 + 0) * 64 + lane];
                short8 b1 = bp[(kb * 8 + wave * 2 + 1) * 64 + lane];
                #pragma unroll
                for (int mt = 0; mt < 4; ++mt) {
                    short8 a = *(const short8*)&lds_h1[(mt * 32 + m0) * 264 + kb * 16 + kq];
                    c2[mt][0] = MFMA(a, b0, c2[mt][0]);
                    c2[mt][1] = MFMA(a, b1, c2[mt][1]);
                }
            }
        }
        // epi2 + layer3 in registers: part[row] = h2[row][col0]*w30 + h2[row][col0+32]*w31
        {
            float part[64];
            #pragma unroll
            for (int mt = 0; mt < 4; ++mt) {
                #pragma unroll
                for (int r = 0; r < 16; ++r) {
                    float h2a = c2[mt][0][r] + b20; h2a = h2a > 0.f ? h2a : 0.f;
                    float h2b = c2[mt][1][r] + b21; h2b = h2b > 0.f ? h2b : 0.f;
                    part[mt * 16 + r] = h2a * w30 + h2b * w31;
                }
            }
            // recursive-halving butterfly over the 32 lanes of each half-wave
            int cnt = 32;
            #pragma unroll
            for (int lvl = 0; lvl < 5; ++lvl) {
                int m = 1 << lvl;
                #pragma unroll
                for (int j = 0; j < cnt; ++j) {
                    bool up = (lane & m) != 0;
                    float send = up ? part[j] : part[j + cnt];
                    float keep = up ? part[j + cnt] : part[j];
                    part[j] = keep + __shfl_xor(send, m, 64);
                }
                cnt >>= 1;
            }
            // lane holds 2 fully-reduced rows; decode surviving original indices
            int base = (lane & 1) * 32 + ((lane >> 1) & 1) * 16 + ((lane >> 2) & 1) * 8
                     + ((lane >> 3) & 1) * 4 + ((lane >> 4) & 1) * 2;
            #pragma unroll
            for (int which = 0; which < 2; ++which) {
                int jr = base + which;
                int mt = jr >> 4, r = jr & 15;
                int row = mt * 32 + (r & 3) + 8 * (r >> 2) + 4 * q;
                pp[wave * 128 + row] = part[which];
            }
        }
        if (t + 1 < TILES_PER_WG) buildD(g + 1);
        __syncthreads();
    }

    // epilogue: store p for last tile
    {
        const int gp = wg * TILES_PER_WG + TILES_PER_WG - 1;
        int bp = gp >> 11, ip = (gp >> 2) & 511, jp = gp & 3;
        if (tid < 128) {
            float v = pp[tid] + pp[128 + tid] + pp[256 + tid] + pp[384 + tid] + b3v;
            out[((size_t)bp * BN + ip) * BN + jp * 128 + tid] = v;
        }
    }
}

// ---------------- kernel 3: in-place symmetrize + zero diagonal ----------------
__global__ void symmetrize(float* __restrict__ out) {
    int b = blockIdx.z, ti = blockIdx.y, tj = blockIdx.x;
    if (tj < ti) return;
    int i = ti * 32 + threadIdx.y, j = tj * 32 + threadIdx.x;
    float* p = out + (size_t)b * BN * BN;
    if (i == j) { p[(size_t)i * BN + j] = 0.f; return; }
    if (j < i) return;
    float a = p[(size_t)i * BN + j];
    float c = p[(size_t)j * BN + i];
    float v = 0.5f * (a + c);
    p[(size_t)i * BN + j] = v;
    p[(size_t)j * BN + i] = v;
}

extern "C" void kernel_launch(void* const* d_in, const int* in_sizes, int n_in,
                              void* d_out, int out_size, void* d_ws, size_t ws_size,
                              hipStream_t stream) {
    const float* node   = (const float*)d_in[0];
    const float* euclid = (const float*)d_in[2];
    const float* W1     = (const float*)d_in[3];
    const float* b1     = (const float*)d_in[4];
    const float* W2     = (const float*)d_in[5];
    const float* b2     = (const float*)d_in[6];
    const float* W3     = (const float*)d_in[7];
    const float* b3     = (const float*)d_in[8];
    float* out = (float*)d_out;

    char* ws = (char*)d_ws;
    float*          PA     = (float*)ws;                                   // 1 MB
    unsigned short* w1c_p  = (unsigned short*)(ws + (1u << 20));                    // 64 KB
    unsigned short* w1b_p  = (unsigned short*)(ws + (1u << 20) + 65536);            // 64 KB
    unsigned short* w2_p   = (unsigned short*)(ws + (1u << 20) + 131072);           // 128 KB
    unsigned short* w1d_f  = (unsigned short*)(ws + (1u << 20) + 262144);           // 8 KB
    unsigned short* node_p = (unsigned short*)(ws + (1u << 20) + 270336);           // 256 KB

    pack_all<<<512, 256, 0, stream>>>(node, W1, W2, w1c_p, w1b_p, w2_p, w1d_f, node_p);
    precompute_pa<<<BN * 2, 256, 0, stream>>>(node, W1, b1, PA);
    edge_main<<<(BN / 128) * BN * 2 / TILES_PER_WG, 256, 0, stream>>>(
        node, euclid, W3, b3, b2, PA, w1c_p, w1b_p, w2_p, w1d_f, node_p, out);
    symmetrize<<<dim3(BN / 32, BN / 32, 2), dim3(32, 32), 0, stream>>>(out);
}

// Round 5
// 268.337 us; speedup vs baseline: 1.3665x; 1.3665x over previous
//
#include <hip/hip_runtime.h>
#include <hip/hip_bf16.h>

// EdgeDetourHead: B=2, N=512, E=128, H=256
// h1 = relu( [ |h_i-h_j| | h_j | e_ij | 1 ] @ [W1c; W1b; w1d; 0] + PA[i] )
// h2 = relu( [h1 | 1] @ [W2; b2] )
// p  = h2 @ W3 + b3 ; out = 0.5*(p+p^T), zero diag
//
// R5 = R3 structure (best so far, 188 us) with pipe-sum reductions:
//  - hj A-frags from global node_p (R4-proven), not LDS: -160 KB LDS/tile
//  - no hi_f/lds_e staging (direct global reads), -1 barrier
//  - prep kernels merged into one launch
//  - epi1/K2/epi2/L3 unchanged from R3 (verified numerics)

#define BN 512
#define EE 128
#define HH 256

typedef __attribute__((ext_vector_type(8)))  short short8;
typedef __attribute__((ext_vector_type(16))) float f32x16;
typedef __attribute__((ext_vector_type(4)))  float f32x4;

static __device__ __forceinline__ unsigned short f2bf(float f) {
    __bf16 h = (__bf16)f;
    return __builtin_bit_cast(unsigned short, h);
}
static __device__ __forceinline__ float bf2f(unsigned short s) {
    return (float)__builtin_bit_cast(__bf16, s);
}
static __device__ __forceinline__ f32x16 zero16() {
    f32x16 v;
    #pragma unroll
    for (int i = 0; i < 16; ++i) v[i] = 0.f;
    return v;
}
#define MFMA(a, b, c) __builtin_amdgcn_mfma_f32_32x32x16_bf16((a), (b), (c), 0, 0, 0)

// ---------------- kernel 0: prep = pack (blocks 0..511) + PA (blocks 512..1535) ----------------
// B-frag (32x32x16): lane l holds B[k=(l>>5)*8+t][n=l&31], t=0..7.
// A-frag:            lane l holds A[m=l&31][k=(l>>5)*8+t].
// Packed linear idx: (frag_id*64 + l)*8 + t -> dwordx4 per lane.
__global__ void prep(const float* __restrict__ node, const float* __restrict__ W1,
                     const float* __restrict__ W2, const float* __restrict__ b1,
                     const float* __restrict__ b2, float* __restrict__ PA,
                     unsigned short* __restrict__ w1c_p, unsigned short* __restrict__ w1b_p,
                     unsigned short* __restrict__ w2_p,  unsigned short* __restrict__ w1d_f,
                     unsigned short* __restrict__ b2_f,  unsigned short* __restrict__ node_p) {
    int blk = blockIdx.x;
    if (blk < 512) {
        int idx = blk * 256 + threadIdx.x;             // 0..131071
        {   // node A-frags: frag (b, j32 0..15, kb 0..7)
            int t = idx & 7, l = (idx >> 3) & 63, kb = (idx >> 9) & 7;
            int j32 = (idx >> 12) & 15, b = (idx >> 16) & 1;
            int j = j32 * 32 + (l & 31), e = kb * 16 + (l >> 5) * 8 + t;
            node_p[idx] = f2bf(node[((size_t)b * BN + j) * EE + e]);
        }
        if (idx < 65536) {                             // W2: kb 0..15
            int t = idx & 7, l = (idx >> 3) & 63, nb = (idx >> 9) & 7, kb = idx >> 12;
            int k = kb * 16 + (l >> 5) * 8 + t, n = nb * 32 + (l & 31);
            w2_p[idx] = f2bf(W2[k * HH + n]);
            if (idx < 32768) {                         // W1c rows 256..383, W1b rows 128..255
                w1c_p[idx] = f2bf(W1[(2 * EE + k) * HH + n]);
                w1b_p[idx] = f2bf(W1[(EE + k) * HH + n]);
            }
        }
        if (idx < 4096) {                              // rank-1 B-frags: w1d (row 384), b2
            int t = idx & 7, l = (idx >> 3) & 63, nb = idx >> 9;
            int n = nb * 32 + (l & 31);
            bool nz = (t == 0 && l < 32);
            w1d_f[idx] = nz ? f2bf(W1[(3 * EE) * HH + n]) : (unsigned short)0;
            b2_f[idx]  = nz ? f2bf(b2[n]) : (unsigned short)0;
        }
    } else {
        int bi = blk - 512;                            // 0..1023
        int h = threadIdx.x;
        const float* nd = node + (size_t)bi * EE;
        float sa = b1[h];
        #pragma unroll 8
        for (int e = 0; e < EE; ++e) sa += nd[e] * W1[e * HH + h];
        PA[bi * HH + h] = sa;
    }
}

// ---------------- kernel 1: fused main (one 128-pair x 256-col tile per WG) ----------------
__global__ __launch_bounds__(256, 2) void edge_main(
    const float* __restrict__ node, const float* __restrict__ euclid,
    const float* __restrict__ W3, const float* __restrict__ b3,
    const float* __restrict__ PA,
    const unsigned short* __restrict__ w1c_p, const unsigned short* __restrict__ w1b_p,
    const unsigned short* __restrict__ w2_p,  const unsigned short* __restrict__ w1d_f,
    const unsigned short* __restrict__ b2_f,  const unsigned short* __restrict__ node_p,
    float* __restrict__ out)
{
    // h1/h2 live at stride 264 over the whole buffer; D aliases the front at stride 136.
    __shared__ __align__(16) unsigned short lds_buf[128 * 264];   // 67584 B
    __shared__ float pp[256];                                     // 1 KB

    const int jt = blockIdx.x, i = blockIdx.y, b = blockIdx.z;
    const int jbase = jt * 128;
    const int tid = threadIdx.x, wave = tid >> 6, lane = tid & 63;
    const int m0 = lane & 31, q = lane >> 5, kq = q * 8;
    const int col0 = wave * 64 + m0;

    // ---- phase 1: build D = |h_i-h_j| bf16, 128x128, stride 136 (direct global reads) ----
    {
        int row = tid >> 1, half = tid & 1;
        const f32x4* nj = (const f32x4*)(node + ((size_t)b * BN + jbase + row) * EE);
        const f32x4* hv = (const f32x4*)(node + ((size_t)b * BN + i) * EE);
        unsigned short* dst = &lds_buf[row * 136 + half * 64];
        #pragma unroll
        for (int g = 0; g < 8; ++g) {
            int c0 = half * 16 + g * 2;                // f32x4 index
            f32x4 a0 = nj[c0], a1 = nj[c0 + 1];
            f32x4 h0 = hv[c0], h1v = hv[c0 + 1];
            short8 pd;
            #pragma unroll
            for (int u = 0; u < 4; ++u) {
                pd[u]     = (short)f2bf(fabsf(a0[u] - h0[u]));
                pd[4 + u] = (short)f2bf(fabsf(a1[u] - h1v[u]));
            }
            *(short8*)(dst + g * 8) = pd;
        }
    }
    __syncthreads();

    // ---- layer 1: D@W1c + hj@W1b + e*w1d ----
    f32x16 acc[4][2];
    #pragma unroll
    for (int mt = 0; mt < 4; ++mt) { acc[mt][0] = zero16(); acc[mt][1] = zero16(); }
    {
        const short8* bc = (const short8*)w1c_p;
        const short8* bb = (const short8*)w1b_p;
        const short8* np = (const short8*)node_p;
        const int npb = b * 128 + jt * 32;             // (b*16 + jt*4)*8 frags
        #pragma unroll
        for (int kb = 0; kb < 8; ++kb) {
            short8 b0 = bc[(kb * 8 + wave * 2 + 0) * 64 + lane];
            short8 b1 = bc[(kb * 8 + wave * 2 + 1) * 64 + lane];
            short8 c0 = bb[(kb * 8 + wave * 2 + 0) * 64 + lane];
            short8 c1 = bb[(kb * 8 + wave * 2 + 1) * 64 + lane];
            #pragma unroll
            for (int mt = 0; mt < 4; ++mt) {
                short8 ad = *(const short8*)&lds_buf[(mt * 32 + m0) * 136 + kb * 16 + kq];
                short8 ah = np[(npb + mt * 8 + kb) * 64 + lane];
                acc[mt][0] = MFMA(ad, b0, acc[mt][0]);
                acc[mt][1] = MFMA(ad, b1, acc[mt][1]);
                acc[mt][0] = MFMA(ah, c0, acc[mt][0]);
                acc[mt][1] = MFMA(ah, c1, acc[mt][1]);
            }
        }
        // rank-1 e*w1d (direct global e reads)
        const float* erow = euclid + ((size_t)b * BN + i) * BN + jbase;
        short8 d0 = ((const short8*)w1d_f)[(wave * 2 + 0) * 64 + lane];
        short8 d1 = ((const short8*)w1d_f)[(wave * 2 + 1) * 64 + lane];
        #pragma unroll
        for (int mt = 0; mt < 4; ++mt) {
            short8 ae;
            #pragma unroll
            for (int u = 0; u < 8; ++u) ae[u] = 0;
            if (lane < 32) ae[0] = (short)f2bf(erow[mt * 32 + m0]);
            acc[mt][0] = MFMA(ae, d0, acc[mt][0]);
            acc[mt][1] = MFMA(ae, d1, acc[mt][1]);
        }
    }
    __syncthreads();   // D dead; h1 overwrites the region

    // ---- epilogue 1: h1 = relu(acc + PA[i]) -> lds_buf stride 264 ----
    {
        const float* paRow = PA + ((size_t)b * BN + i) * HH;
        float pa0 = paRow[col0], pa1 = paRow[col0 + 32];
        int rq = 4 * q;
        #pragma unroll
        for (int mt = 0; mt < 4; ++mt) {
            #pragma unroll
            for (int r = 0; r < 16; ++r) {
                int row = mt * 32 + (r & 3) + 8 * (r >> 2) + rq;
                float v0 = acc[mt][0][r] + pa0; v0 = v0 > 0.f ? v0 : 0.f;
                float v1 = acc[mt][1][r] + pa1; v1 = v1 > 0.f ? v1 : 0.f;
                lds_buf[row * 264 + col0]      = f2bf(v0);
                lds_buf[row * 264 + col0 + 32] = f2bf(v1);
            }
        }
    }
    __syncthreads();

    // ---- layer 2: h1@W2 + 1*b2 ----
    f32x16 c2[4][2];
    #pragma unroll
    for (int mt = 0; mt < 4; ++mt) { c2[mt][0] = zero16(); c2[mt][1] = zero16(); }
    {
        const short8* bp = (const short8*)w2_p;
        #pragma unroll
        for (int kb = 0; kb < 16; ++kb) {
            short8 b0 = bp[(kb * 8 + wave * 2 + 0) * 64 + lane];
            short8 b1 = bp[(kb * 8 + wave * 2 + 1) * 64 + lane];
            #pragma unroll
            for (int mt = 0; mt < 4; ++mt) {
                short8 a = *(const short8*)&lds_buf[(mt * 32 + m0) * 264 + kb * 16 + kq];
                c2[mt][0] = MFMA(a, b0, c2[mt][0]);
                c2[mt][1] = MFMA(a, b1, c2[mt][1]);
            }
        }
        short8 aone;
        #pragma unroll
        for (int u = 0; u < 8; ++u) aone[u] = 0;
        if (lane < 32) aone[0] = (short)0x3F80;        // bf16 1.0
        short8 e0 = ((const short8*)b2_f)[(wave * 2 + 0) * 64 + lane];
        short8 e1 = ((const short8*)b2_f)[(wave * 2 + 1) * 64 + lane];
        #pragma unroll
        for (int mt = 0; mt < 4; ++mt) {
            c2[mt][0] = MFMA(aone, e0, c2[mt][0]);
            c2[mt][1] = MFMA(aone, e1, c2[mt][1]);
        }
    }
    __syncthreads();   // h1 dead

    // ---- epilogue 2: h2 = relu(c2) -> lds_buf ----
    {
        int rq = 4 * q;
        #pragma unroll
        for (int mt = 0; mt < 4; ++mt) {
            #pragma unroll
            for (int r = 0; r < 16; ++r) {
                int row = mt * 32 + (r & 3) + 8 * (r >> 2) + rq;
                float v0 = c2[mt][0][r] > 0.f ? c2[mt][0][r] : 0.f;
                float v1 = c2[mt][1][r] > 0.f ? c2[mt][1][r] : 0.f;
                lds_buf[row * 264 + col0]      = f2bf(v0);
                lds_buf[row * 264 + col0 + 32] = f2bf(v1);
            }
        }
    }
    __syncthreads();

    // ---- layer 3: p = h2 @ W3 + b3 (fp32, 2-way split-K) ----
    {
        int row = tid >> 1, halfc = (tid & 1) * 128;
        float s = 0.f;
        #pragma unroll
        for (int k = 0; k < 16; ++k) {
            short8 h8 = *(const short8*)&lds_buf[row * 264 + halfc + k * 8];
            #pragma unroll
            for (int u = 0; u < 8; ++u)
                s += bf2f((unsigned short)h8[u]) * W3[halfc + k * 8 + u];
        }
        pp[tid] = s;
    }
    __syncthreads();
    if (tid < 128) {
        float v = pp[tid * 2] + pp[tid * 2 + 1] + b3[0];
        out[((size_t)b * BN + i) * BN + jbase + tid] = v;
    }
}

// ---------------- kernel 2: in-place symmetrize + zero diagonal ----------------
__global__ void symmetrize(float* __restrict__ out) {
    int b = blockIdx.z, ti = blockIdx.y, tj = blockIdx.x;
    if (tj < ti) return;
    int i = ti * 32 + threadIdx.y, j = tj * 32 + threadIdx.x;
    float* p = out + (size_t)b * BN * BN;
    if (i == j) { p[(size_t)i * BN + j] = 0.f; return; }
    if (j < i) return;
    float a = p[(size_t)i * BN + j];
    float c = p[(size_t)j * BN + i];
    float v = 0.5f * (a + c);
    p[(size_t)i * BN + j] = v;
    p[(size_t)j * BN + i] = v;
}

extern "C" void kernel_launch(void* const* d_in, const int* in_sizes, int n_in,
                              void* d_out, int out_size, void* d_ws, size_t ws_size,
                              hipStream_t stream) {
    const float* node   = (const float*)d_in[0];
    const float* euclid = (const float*)d_in[2];
    const float* W1     = (const float*)d_in[3];
    const float* b1     = (const float*)d_in[4];
    const float* W2     = (const float*)d_in[5];
    const float* b2     = (const float*)d_in[6];
    const float* W3     = (const float*)d_in[7];
    const float* b3     = (const float*)d_in[8];
    float* out = (float*)d_out;

    char* ws = (char*)d_ws;
    float*          PA     = (float*)ws;                                    // 1 MB
    unsigned short* w1c_p  = (unsigned short*)(ws + (1u << 20));            // 64 KB
    unsigned short* w1b_p  = (unsigned short*)(ws + (1u << 20) + 65536);    // 64 KB
    unsigned short* w2_p   = (unsigned short*)(ws + (1u << 20) + 131072);   // 128 KB
    unsigned short* w1d_f  = (unsigned short*)(ws + (1u << 20) + 262144);   // 8 KB
    unsigned short* b2_f   = (unsigned short*)(ws + (1u << 20) + 270336);   // 8 KB
    unsigned short* node_p = (unsigned short*)(ws + (1u << 20) + 278528);   // 256 KB

    prep<<<1536, 256, 0, stream>>>(node, W1, W2, b1, b2, PA,
                                   w1c_p, w1b_p, w2_p, w1d_f, b2_f, node_p);
    edge_main<<<dim3(BN / 128, BN, 2), 256, 0, stream>>>(
        node, euclid, W3, b3, PA, w1c_p, w1b_p, w2_p, w1d_f, b2_f, node_p, out);
    symmetrize<<<dim3(BN / 32, BN / 32, 2), dim3(32, 32), 0, stream>>>(out);
}

// Round 6
// 236.096 us; speedup vs baseline: 1.5531x; 1.1366x over previous
//
#include <hip/hip_runtime.h>
#include <hip/hip_bf16.h>

// EdgeDetourHead: B=2, N=512, E=128, H=256
// h1 = relu( [ |h_i-h_j| | h_j | e_ij ] @ [W1c; W1b; w1d] + PA[i] )  (PA = h_i@W1a + b1, fp32)
// h2 = relu( h1@W2 + b2 ) ;  p = h2@W3 + b3 ;  out = 0.5*(p+p^T), zero diag
//
// R6: fully TRANSPOSED dataflow. Every GEMM computes C^T with weights as the
// MFMA A operand (packed weight arrays double as A-frags of W^T) and pair-data
// as the B operand read row-major from LDS via aligned ds_read_b128.
//  - epi1: 4 consecutive feats/lane -> 32 ds_write_b64 (was 128 ds_write_b16)
//  - layer 3 entirely in registers from C2^T (epi2 + its barrier + cvts gone)
//  - hj built into LDS during D-build (R5 regression lesson: keep it off VMEM)
//  - b2 applied fp32 in L3; PA applied fp32 in epi1 via wave-uniform s_loads

#define BN 512
#define EE 128
#define HH 256

typedef __attribute__((ext_vector_type(8)))  short short8;
typedef __attribute__((ext_vector_type(4)))  short short4v;
typedef __attribute__((ext_vector_type(16))) float f32x16;
typedef __attribute__((ext_vector_type(4)))  float f32x4;

static __device__ __forceinline__ unsigned short f2bf(float f) {
    __bf16 h = (__bf16)f;
    return __builtin_bit_cast(unsigned short, h);
}
static __device__ __forceinline__ f32x16 zero16() {
    f32x16 v;
    #pragma unroll
    for (int i = 0; i < 16; ++i) v[i] = 0.f;
    return v;
}
#define MFMA(a, b, c) __builtin_amdgcn_mfma_f32_32x32x16_bf16((a), (b), (c), 0, 0, 0)

// ---------------- kernel 0: prep = weight pack (blocks 0..255) + PA (blocks 256..1279) ----
// Packed frag idx = ((kb*8 + mtile)*64 + l)*8 + t ; value W[kb*16+(l>>5)*8+t][mtile*32+(l&31)]
// == B-frag of W == A-frag of W^T. Reused directly by the transposed kernel.
__global__ void prep(const float* __restrict__ node, const float* __restrict__ W1,
                     const float* __restrict__ W2, const float* __restrict__ b1,
                     float* __restrict__ PA,
                     unsigned short* __restrict__ w1c_p, unsigned short* __restrict__ w1b_p,
                     unsigned short* __restrict__ w2_p,  unsigned short* __restrict__ w1d_f) {
    int blk = blockIdx.x;
    if (blk < 256) {
        int idx = blk * 256 + threadIdx.x;             // 0..65535
        {                                              // W2^T A-frags: kb 0..15
            int t = idx & 7, l = (idx >> 3) & 63, mt = (idx >> 9) & 7, kb = idx >> 12;
            int k = kb * 16 + (l >> 5) * 8 + t, m = mt * 32 + (l & 31);
            w2_p[idx] = f2bf(W2[k * HH + m]);
            if (idx < 32768) {                         // W1c^T, W1b^T: kb 0..7
                w1c_p[idx] = f2bf(W1[(2 * EE + k) * HH + m]);
                w1b_p[idx] = f2bf(W1[(EE + k) * HH + m]);
            }
        }
        if (idx < 4096) {                              // w1d^T rank-1 A-frags (k=0 col)
            int t = idx & 7, l = (idx >> 3) & 63, mt = idx >> 9;
            int m = mt * 32 + (l & 31);
            bool nz = (t == 0 && l < 32);
            w1d_f[idx] = nz ? f2bf(W1[(3 * EE) * HH + m]) : (unsigned short)0;
        }
    } else {
        int bi = blk - 256;                            // 0..1023
        int h = threadIdx.x;
        const float* nd = node + (size_t)bi * EE;
        float sa = b1[h];
        #pragma unroll 8
        for (int e = 0; e < EE; ++e) sa += nd[e] * W1[e * HH + h];
        PA[bi * HH + h] = sa;
    }
}

// ---------------- kernel 1: fused main, transposed (one 128-pair tile per WG) ----------------
// Wave w owns feature m-tiles {2w, 2w+1} (64 feats) x all 4 pair n-tiles -> 8 acc tiles.
__global__ __launch_bounds__(256, 2) void edge_main(
    const float* __restrict__ node, const float* __restrict__ euclid,
    const float* __restrict__ W3, const float* __restrict__ b3,
    const float* __restrict__ b2v, const float* __restrict__ PA,
    const unsigned short* __restrict__ w1c_p, const unsigned short* __restrict__ w1b_p,
    const unsigned short* __restrict__ w2_p,  const unsigned short* __restrict__ w1d_f,
    float* __restrict__ out)
{
    // Phase 1/K1: D [128][136] + hj [128][136] (69632 B). epi1 on: h1 [128][264] (67584 B).
    __shared__ __align__(16) unsigned short lds_buf[2 * 128 * 136];
    __shared__ float pp[512];

    const int jt = blockIdx.x, i = blockIdx.y, b = blockIdx.z;
    const int jbase = jt * 128;
    const int tid = threadIdx.x, wave = tid >> 6, lane = tid & 63;
    const int m0 = lane & 31, q = lane >> 5;

    unsigned short* ldsD  = lds_buf;
    unsigned short* ldsHJ = lds_buf + 128 * 136;
    unsigned short* ldsH1 = lds_buf;                   // overwrites D+hj after K1

    // ---- phase 1: build D=|h_i-h_j| and hj (bf16) row-major [pair][e], stride 136 ----
    {
        int row = tid >> 1, half = tid & 1;
        const f32x4* nj = (const f32x4*)(node + ((size_t)b * BN + jbase + row) * EE);
        const f32x4* hv = (const f32x4*)(node + ((size_t)b * BN + i) * EE);
        #pragma unroll
        for (int g = 0; g < 8; ++g) {
            int c0 = half * 16 + g * 2;                // f32x4 index
            f32x4 a0 = nj[c0], a1 = nj[c0 + 1];
            f32x4 h0 = hv[c0], h1v = hv[c0 + 1];
            short8 pd, ph;
            #pragma unroll
            for (int u = 0; u < 4; ++u) {
                pd[u]     = (short)f2bf(fabsf(a0[u] - h0[u]));
                pd[4 + u] = (short)f2bf(fabsf(a1[u] - h1v[u]));
                ph[u]     = (short)f2bf(a0[u]);
                ph[4 + u] = (short)f2bf(a1[u]);
            }
            int off = row * 136 + half * 64 + g * 8;
            *(short8*)&ldsD[off]  = pd;
            *(short8*)&ldsHJ[off] = ph;
        }
    }
    __syncthreads();

    // ---- layer 1 (transposed): C1^T = W1c^T@D^T + W1b^T@hj^T + w1d^T@e^T ----
    f32x16 acc[2][4];
    #pragma unroll
    for (int mt = 0; mt < 2; ++mt)
        #pragma unroll
        for (int nt = 0; nt < 4; ++nt) acc[mt][nt] = zero16();
    {
        const short8* wc = (const short8*)w1c_p;
        const short8* wb = (const short8*)w1b_p;
        const int mtg = wave * 2;
        #pragma unroll
        for (int kb = 0; kb < 8; ++kb) {
            short8 ac0 = wc[(kb * 8 + mtg + 0) * 64 + lane];
            short8 ac1 = wc[(kb * 8 + mtg + 1) * 64 + lane];
            short8 ab0 = wb[(kb * 8 + mtg + 0) * 64 + lane];
            short8 ab1 = wb[(kb * 8 + mtg + 1) * 64 + lane];
            #pragma unroll
            for (int nt = 0; nt < 4; ++nt) {
                int off = (nt * 32 + m0) * 136 + kb * 16 + q * 8;
                short8 bD  = *(const short8*)&ldsD[off];
                short8 bHJ = *(const short8*)&ldsHJ[off];
                acc[0][nt] = MFMA(ac0, bD, acc[0][nt]);
                acc[1][nt] = MFMA(ac1, bD, acc[1][nt]);
                acc[0][nt] = MFMA(ab0, bHJ, acc[0][nt]);
                acc[1][nt] = MFMA(ab1, bHJ, acc[1][nt]);
            }
        }
        // rank-1 e*w1d: A = w1d^T col frag, B = e row frag
        const float* erow = euclid + ((size_t)b * BN + i) * BN + jbase;
        short8 aw0 = ((const short8*)w1d_f)[(mtg + 0) * 64 + lane];
        short8 aw1 = ((const short8*)w1d_f)[(mtg + 1) * 64 + lane];
        #pragma unroll
        for (int nt = 0; nt < 4; ++nt) {
            short8 be;
            #pragma unroll
            for (int u = 0; u < 8; ++u) be[u] = 0;
            if (lane < 32) be[0] = (short)f2bf(erow[nt * 32 + m0]);
            acc[0][nt] = MFMA(aw0, be, acc[0][nt]);
            acc[1][nt] = MFMA(aw1, be, acc[1][nt]);
        }
    }
    __syncthreads();   // D + hj dead

    // ---- epi1: h1[pair][feat] = relu(C1^T + PA[feat]); 4 consecutive feats -> b64 ----
    {
        const float* paB = PA + ((size_t)b * BN + i) * HH;
        #pragma unroll
        for (int mt = 0; mt < 2; ++mt) {
            #pragma unroll
            for (int rg = 0; rg < 4; ++rg) {
                int f0 = wave * 64 + mt * 32 + rg * 8;         // wave-uniform
                f32x4 plo = *(const f32x4*)&paB[f0];
                f32x4 phi = *(const f32x4*)&paB[f0 + 4];
                f32x4 pav;
                #pragma unroll
                for (int u = 0; u < 4; ++u) pav[u] = q ? phi[u] : plo[u];
                #pragma unroll
                for (int nt = 0; nt < 4; ++nt) {
                    short4v w;
                    #pragma unroll
                    for (int u = 0; u < 4; ++u) {
                        float v = acc[mt][nt][rg * 4 + u] + pav[u];
                        v = v > 0.f ? v : 0.f;
                        w[u] = (short)f2bf(v);
                    }
                    *(short4v*)&ldsH1[(nt * 32 + m0) * 264 + f0 + 4 * q] = w;
                }
            }
        }
    }
    __syncthreads();

    // ---- layer 2 (transposed): C2^T = W2^T @ h1^T ----
    f32x16 c2[2][4];
    #pragma unroll
    for (int mt = 0; mt < 2; ++mt)
        #pragma unroll
        for (int nt = 0; nt < 4; ++nt) c2[mt][nt] = zero16();
    {
        const short8* w2f = (const short8*)w2_p;
        const int mtg = wave * 2;
        #pragma unroll
        for (int kb = 0; kb < 16; ++kb) {
            short8 a0 = w2f[(kb * 8 + mtg + 0) * 64 + lane];
            short8 a1 = w2f[(kb * 8 + mtg + 1) * 64 + lane];
            #pragma unroll
            for (int nt = 0; nt < 4; ++nt) {
                short8 bh = *(const short8*)&ldsH1[(nt * 32 + m0) * 264 + kb * 16 + q * 8];
                c2[0][nt] = MFMA(a0, bh, c2[0][nt]);
                c2[1][nt] = MFMA(a1, bh, c2[1][nt]);
            }
        }
    }

    // ---- layer 3 in registers: s[nt] = sum_feat relu(c2+b2[feat]) * W3[feat] ----
    {
        float s[4] = {0.f, 0.f, 0.f, 0.f};
        #pragma unroll
        for (int mt = 0; mt < 2; ++mt) {
            #pragma unroll
            for (int rg = 0; rg < 4; ++rg) {
                int f0 = wave * 64 + mt * 32 + rg * 8;         // wave-uniform
                f32x4 blo = *(const f32x4*)&b2v[f0];
                f32x4 bhi = *(const f32x4*)&b2v[f0 + 4];
                f32x4 wlo = *(const f32x4*)&W3[f0];
                f32x4 whi = *(const f32x4*)&W3[f0 + 4];
                #pragma unroll
                for (int u = 0; u < 4; ++u) {
                    float bb = q ? bhi[u] : blo[u];
                    float ww = q ? whi[u] : wlo[u];
                    #pragma unroll
                    for (int nt = 0; nt < 4; ++nt) {
                        float h2 = c2[mt][nt][rg * 4 + u] + bb;
                        h2 = h2 > 0.f ? h2 : 0.f;
                        s[nt] += h2 * ww;
                    }
                }
            }
        }
        #pragma unroll
        for (int nt = 0; nt < 4; ++nt)
            s[nt] += __shfl_xor(s[nt], 32, 64);       // fold q-halves
        if (lane < 32) {
            #pragma unroll
            for (int nt = 0; nt < 4; ++nt)
                pp[wave * 128 + nt * 32 + lane] = s[nt];
        }
    }
    __syncthreads();
    if (tid < 128) {
        float v = pp[tid] + pp[128 + tid] + pp[256 + tid] + pp[384 + tid] + b3[0];
        out[((size_t)b * BN + i) * BN + jbase + tid] = v;
    }
}

// ---------------- kernel 2: in-place symmetrize + zero diagonal ----------------
__global__ void symmetrize(float* __restrict__ out) {
    int b = blockIdx.z, ti = blockIdx.y, tj = blockIdx.x;
    if (tj < ti) return;
    int i = ti * 32 + threadIdx.y, j = tj * 32 + threadIdx.x;
    float* p = out + (size_t)b * BN * BN;
    if (i == j) { p[(size_t)i * BN + j] = 0.f; return; }
    if (j < i) return;
    float a = p[(size_t)i * BN + j];
    float c = p[(size_t)j * BN + i];
    float v = 0.5f * (a + c);
    p[(size_t)i * BN + j] = v;
    p[(size_t)j * BN + i] = v;
}

extern "C" void kernel_launch(void* const* d_in, const int* in_sizes, int n_in,
                              void* d_out, int out_size, void* d_ws, size_t ws_size,
                              hipStream_t stream) {
    const float* node   = (const float*)d_in[0];
    const float* euclid = (const float*)d_in[2];
    const float* W1     = (const float*)d_in[3];
    const float* b1     = (const float*)d_in[4];
    const float* W2     = (const float*)d_in[5];
    const float* b2     = (const float*)d_in[6];
    const float* W3     = (const float*)d_in[7];
    const float* b3     = (const float*)d_in[8];
    float* out = (float*)d_out;

    char* ws = (char*)d_ws;
    float*          PA    = (float*)ws;                                   // 1 MB
    unsigned short* w1c_p = (unsigned short*)(ws + (1u << 20));           // 64 KB
    unsigned short* w1b_p = (unsigned short*)(ws + (1u << 20) + 65536);   // 64 KB
    unsigned short* w2_p  = (unsigned short*)(ws + (1u << 20) + 131072);  // 128 KB
    unsigned short* w1d_f = (unsigned short*)(ws + (1u << 20) + 262144);  // 8 KB

    prep<<<1280, 256, 0, stream>>>(node, W1, W2, b1, PA, w1c_p, w1b_p, w2_p, w1d_f);
    edge_main<<<dim3(BN / 128, BN, 2), 256, 0, stream>>>(
        node, euclid, W3, b3, b2, PA, w1c_p, w1b_p, w2_p, w1d_f, out);
    symmetrize<<<dim3(BN / 32, BN / 32, 2), dim3(32, 32), 0, stream>>>(out);
}